// Round 13
// baseline (88.700 us; speedup 1.0000x reference)
//
#include <hip/hip_runtime.h>
#include <math.h>

#define G_N   2048
#define NT    32
#define NP    32
#define NR    64
#define NRAY  (NT * NP)
#define PLANE 8196     // floats per ray-plane: 2048*4 + 4 pad -> +4 bank skew
#define QCULL -30.0f   // keep gaussian iff max_t q(t) > 2^-30 (contrib <= 1e-9)

// ---------------------------------------------------------------------------
// k_main: one block per 4 rays (grid 256 = 1 block/CU), 512 thr = 8 waves
// (2 waves/SIMD). r12 evidence: cull works (n_act ~20-40%); remaining k_main
// cost = phase-0 redundancy + hot-loop LDS reads. 4 rays/block halves BOTH
// per CU: one 2048-g precompute per CU, and each ds_read_b128 serves
// 4 rays x 4 t-samples (64B distinct, disjoint bank quads).
// Phase 0: precompute + per-ray cull (max_t q(t) > QCULL) + ballot-compact
//          into 4 bank-skewed planes (full 2048 slots -> no overflow risk).
// Phase 1: lane = (ray r = lane>>4, tslot ts = lane&15), 4 t-samples/lane;
//          wave wv strides compacted records j = wv, wv+8, ...
// Phase 2/3: cross-wave LDS reduce, per-ray shuffle scan, transmittance, out.
// ---------------------------------------------------------------------------
__global__ __launch_bounds__(512) void k_main(
    const float* __restrict__ means, const float* __restrict__ scales,
    const float* __restrict__ rots, const float* __restrict__ opacs,
    const float* __restrict__ feats, const float* __restrict__ cam,
    float* __restrict__ out) {
  __shared__ float coef[4 * PLANE];   // 131,136 B (compacted records per ray)
  __shared__ float red[2][8][256];    // 16,384 B
  __shared__ int   nact[4];

  const int tid  = threadIdx.x;
  const int lane = tid & 63;
  const int wv   = tid >> 6;          // 0..7
  const int ray0 = blockIdx.x * 4;
  const int ti   = ray0 >> 5;
  const int pj0  = ray0 & 31;

  if (tid < 4) nact[tid] = 0;
  __syncthreads();

  const float dth = (float)(M_PI / 2.0 / (NT - 1));
  const float dph = (float)(M_PI / (NP - 1));
  float sth, cth;
  sincosf((float)ti * dth, &sth, &cth);
  const float dz = cth, dzz = dz * dz;

  float dX[4], dY[4], dXX[4], dYY[4], dXY[4], dXZ[4], dYZ[4];
  #pragma unroll
  for (int r = 0; r < 4; ++r) {
    float ph = (float)(-M_PI / 2.0) + (float)(pj0 + r) * dph;
    float sp, cp;
    sincosf(ph, &sp, &cp);
    float dx = sth * cp, dy = sth * sp;
    dX[r] = dx; dY[r] = dy;
    dXX[r] = dx * dx; dYY[r] = dy * dy;
    dXY[r] = 2.f * dx * dy; dXZ[r] = 2.f * dx * dz; dYZ[r] = 2.f * dy * dz;
  }

  const float cx = cam[0], cy = cam[1], cz = cam[2];
  const float c      = -0.7213475204444817f;   // -0.5 * log2(e)
  const float l2e    = 1.4426950408889634f;
  const float n2l2e  = -2.8853900817779268f;   // -2*log2(e)
  const float SH_C0  = 0.28209479177387814f;

  // ---------------- Phase 0: precompute + cull + ballot-compact ------------
  #pragma unroll
  for (int i = 0; i < G_N / 512; ++i) {
    int g = tid + i * 512;
    float i0 = __builtin_amdgcn_exp2f(n2l2e * scales[3*g+0]);
    float i1 = __builtin_amdgcn_exp2f(n2l2e * scales[3*g+1]);
    float i2 = __builtin_amdgcn_exp2f(n2l2e * scales[3*g+2]);

    float qw = rots[4*g+0], qx = rots[4*g+1], qy = rots[4*g+2], qz = rots[4*g+3];
    float inv = __builtin_amdgcn_rsqf(qw*qw + qx*qx + qy*qy + qz*qz);
    qw *= inv; qx *= inv; qy *= inv; qz *= inv;

    float R00 = 1.f - 2.f*(qy*qy + qz*qz), R01 = 2.f*(qx*qy - qw*qz), R02 = 2.f*(qx*qz + qw*qy);
    float R10 = 2.f*(qx*qy + qw*qz), R11 = 1.f - 2.f*(qx*qx + qz*qz), R12 = 2.f*(qy*qz - qw*qx);
    float R20 = 2.f*(qx*qz - qw*qy), R21 = 2.f*(qy*qz + qw*qx), R22 = 1.f - 2.f*(qx*qx + qy*qy);

    float p00 = c*(R00*R00*i0 + R01*R01*i1 + R02*R02*i2);
    float p11 = c*(R10*R10*i0 + R11*R11*i1 + R12*R12*i2);
    float p22 = c*(R20*R20*i0 + R21*R21*i1 + R22*R22*i2);
    float p01 = c*(R00*R10*i0 + R01*R11*i1 + R02*R12*i2);
    float p02 = c*(R00*R20*i0 + R01*R21*i1 + R02*R22*i2);
    float p12 = c*(R10*R20*i0 + R11*R21*i1 + R12*R22*i2);

    float ox = cx - means[3*g+0], oy = cy - means[3*g+1], oz = cz - means[3*g+2];
    float Px = p00*ox + p01*oy + p02*oz;      // = c * (P om)
    float Py = p01*ox + p11*oy + p12*oz;
    float Pz = p02*ox + p12*oy + p22*oz;
    float Cq = ox*Px + oy*Py + oz*Pz;         // = c * om^T P om

    float u  = __builtin_amdgcn_exp2f(-l2e * opacs[g]);
    float Cf = Cq - __builtin_amdgcn_logf(1.0f + u);   // + log2(sigmoid)

    float a0 = fmaxf(SH_C0*feats[3*g+0] + 0.5f, 0.f);
    float a1 = fmaxf(SH_C0*feats[3*g+1] + 0.5f, 0.f);
    float a2 = fmaxf(SH_C0*feats[3*g+2] + 0.5f, 0.f);
    float alb = (a0 + a1 + a2) * (1.0f/3.0f);

    #pragma unroll
    for (int r = 0; r < 4; ++r) {
      float A = p00*dXX[r] + p11*dYY[r] + p22*dzz + p01*dXY[r] + p02*dXZ[r] + p12*dYZ[r];
      float B = 2.f * (Px*dX[r] + Py*dY[r] + Pz*dz);
      // max over t in [0.5, 2.5]: A < 0 strictly (P positive definite)
      float tstar = fminf(2.5f, fmaxf(0.5f, -B / (2.f * A)));
      float qm = fmaf(fmaf(A, tstar, B), tstar, Cf);
      bool keep = qm > QCULL;
      unsigned long long m = __ballot(keep);
      int base;
      if (lane == 0) base = atomicAdd(&nact[r], __popcll(m));
      base = __shfl(base, 0, 64);
      if (keep) {
        int slot = base + __popcll(m & ((1ull << lane) - 1ull));
        *(float4*)&coef[r * PLANE + slot * 4] = make_float4(A, B, Cf, alb);
      }
    }
  }
  __syncthreads();

  // ---------------- Phase 1: hot loop over compacted records ----------------
  const int r  = lane >> 4;           // ray within quad
  const int ts = lane & 15;           // t-slot
  const float tstep = 2.0f / 63.0f;
  const float t0 = 0.5f + (float)ts * tstep;
  const float t1 = t0 + 16.f * tstep;
  const float t2 = t0 + 32.f * tstep;
  const float t3 = t0 + 48.f * tstep;

  const int n = nact[r];
  const float4* basep = (const float4*)&coef[r * PLANE];
  float d0 = 0.f, d1 = 0.f, d2 = 0.f, d3 = 0.f;
  float h0 = 0.f, h1 = 0.f, h2 = 0.f, h3 = 0.f;
  for (int j = wv; j < n; j += 8) {
    float4 e = basep[j];
    float q0 = fmaf(fmaf(e.x, t0, e.y), t0, e.z);
    float q1 = fmaf(fmaf(e.x, t1, e.y), t1, e.z);
    float q2 = fmaf(fmaf(e.x, t2, e.y), t2, e.z);
    float q3 = fmaf(fmaf(e.x, t3, e.y), t3, e.z);
    float x0 = __builtin_amdgcn_exp2f(q0);
    float x1 = __builtin_amdgcn_exp2f(q1);
    float x2 = __builtin_amdgcn_exp2f(q2);
    float x3 = __builtin_amdgcn_exp2f(q3);
    d0 += x0; h0 = fmaf(x0, e.w, h0);
    d1 += x1; h1 = fmaf(x1, e.w, h1);
    d2 += x2; h2 = fmaf(x2, e.w, h2);
    d3 += x3; h3 = fmaf(x3, e.w, h3);
  }

  // ---------------- Phase 2: stash partials ----------------
  red[0][wv][r*64 + ts     ] = d0;  red[1][wv][r*64 + ts     ] = h0;
  red[0][wv][r*64 + ts + 16] = d1;  red[1][wv][r*64 + ts + 16] = h1;
  red[0][wv][r*64 + ts + 32] = d2;  red[1][wv][r*64 + ts + 32] = h2;
  red[0][wv][r*64 + ts + 48] = d3;  red[1][wv][r*64 + ts + 48] = h3;
  __syncthreads();

  // ---------------- Phase 3: reduce + scan + store (first 4 waves) ---------
  if (tid < 256) {
    const int rr = tid >> 6;
    const int t  = tid & 63;
    int idx = rr * 64 + t;
    float D  = ((red[0][0][idx] + red[0][1][idx]) + (red[0][2][idx] + red[0][3][idx]))
             + ((red[0][4][idx] + red[0][5][idx]) + (red[0][6][idx] + red[0][7][idx]));
    float Rh = ((red[1][0][idx] + red[1][1][idx]) + (red[1][2][idx] + red[1][3][idx]))
             + ((red[1][4][idx] + red[1][5][idx]) + (red[1][6][idx] + red[1][7][idx]));
    const float step = 1.0f * 0.03125f;   // C_LIGHT * DELTA_T
    float s = D * step;
    float inc = s;
    #pragma unroll
    for (int off = 1; off < 64; off <<= 1) {
      float v = __shfl_up(inc, off, 64);
      if (t >= off) inc += v;
    }
    float excl = inc - s;
    float T = __builtin_amdgcn_exp2f(-1.4426950408889634f * excl);
    float tv = 0.5f + (float)t * tstep;
    float res = Rh * T / (tv * tv + 1e-8f) * sth;
    out[t * NRAY + ray0 + rr] = res;
  }
}

// ---------------------------------------------------------------------------
// Histogram. One block per t bin; sum 1024 rays.
// ---------------------------------------------------------------------------
__global__ __launch_bounds__(256) void k_hist(const float* __restrict__ res,
                                              float* __restrict__ hist) {
  const int t = blockIdx.x;
  const int tid = threadIdx.x;
  float s = 0.f;
  #pragma unroll
  for (int rr = tid; rr < NRAY; rr += 256) s += res[t * NRAY + rr];
  #pragma unroll
  for (int off = 32; off > 0; off >>= 1) s += __shfl_down(s, off, 64);
  __shared__ float sm[4];
  if ((tid & 63) == 0) sm[tid >> 6] = s;
  __syncthreads();
  if (tid == 0) {
    const float dtdp = (float)((M_PI / 2.0 / NT) * (M_PI / NP));
    hist[t] = ((sm[0] + sm[1]) + (sm[2] + sm[3])) * dtdp;
  }
}

extern "C" void kernel_launch(void* const* d_in, const int* in_sizes, int n_in,
                              void* d_out, int out_size, void* d_ws, size_t ws_size,
                              hipStream_t stream) {
  const float* means  = (const float*)d_in[0];
  const float* scales = (const float*)d_in[1];
  const float* rots   = (const float*)d_in[2];
  const float* opacs  = (const float*)d_in[3];
  const float* feats  = (const float*)d_in[4];
  const float* cam    = (const float*)d_in[5];

  float* out = (float*)d_out;

  k_main<<<NRAY / 4, 512, 0, stream>>>(means, scales, rots, opacs, feats, cam, out);
  k_hist<<<NR,       256, 0, stream>>>(out, out + NR * NRAY);
}

// Round 14
// 85.207 us; speedup vs baseline: 1.0410x; 1.0410x over previous
//
#include <hip/hip_runtime.h>
#include <math.h>

#define G_N   2048
#define NT    32
#define NP    32
#define NR    64
#define NRAY  (NT * NP)
#define PLANE 8196     // floats per ray-plane: 2048*4 + 4 pad -> +4 bank skew
#define QCULL -30.0f   // keep gaussian iff max_t q(t) > 2^-30 (contrib <= 1e-9)

// ---------------------------------------------------------------------------
// k_main: one block per 2 rays (grid 512 -> 2 blocks/CU), 512 thr = 8 waves
// (4 waves/SIMD). Best measured config (r12: 84.3us total, ~9us my-portion).
// r13 (4 rays/block, 1 block/CU) regressed: phase-0 redundancy halved but TLP
// halved too -- latency-hiding wins for the cull-shortened hot loop.
// Phase 0: precompute + per-ray cull (max_t q(t) > QCULL) + ballot-compact
//          into 2 bank-skewed planes.
// Phase 1: lane = (ray r = lane>>5, tslot ts = lane&31), 2 t-samples/lane;
//          wave wv strides compacted records j = wv, wv+8, ...
// Phase 2/3: cross-wave LDS reduce, per-ray shuffle scan, transmittance, out.
// ---------------------------------------------------------------------------
__global__ __launch_bounds__(512, 4) void k_main(
    const float* __restrict__ means, const float* __restrict__ scales,
    const float* __restrict__ rots, const float* __restrict__ opacs,
    const float* __restrict__ feats, const float* __restrict__ cam,
    float* __restrict__ out) {
  __shared__ float coef[2 * PLANE];   // 65,568 B (compacted records per ray)
  __shared__ float red[2][8][128];    // 8,192 B
  __shared__ int   nact[2];

  const int tid  = threadIdx.x;
  const int lane = tid & 63;
  const int wv   = tid >> 6;          // 0..7
  const int ray0 = blockIdx.x * 2;
  const int ti   = ray0 >> 5;
  const int pj0  = ray0 & 31;

  if (tid < 2) nact[tid] = 0;
  __syncthreads();

  const float dth = (float)(M_PI / 2.0 / (NT - 1));
  const float dph = (float)(M_PI / (NP - 1));
  float sth, cth;
  sincosf((float)ti * dth, &sth, &cth);
  const float dz = cth, dzz = dz * dz;

  float dX[2], dY[2], dXX[2], dYY[2], dXY[2], dXZ[2], dYZ[2];
  #pragma unroll
  for (int r = 0; r < 2; ++r) {
    float ph = (float)(-M_PI / 2.0) + (float)(pj0 + r) * dph;
    float sp, cp;
    sincosf(ph, &sp, &cp);
    float dx = sth * cp, dy = sth * sp;
    dX[r] = dx; dY[r] = dy;
    dXX[r] = dx * dx; dYY[r] = dy * dy;
    dXY[r] = 2.f * dx * dy; dXZ[r] = 2.f * dx * dz; dYZ[r] = 2.f * dy * dz;
  }

  const float cx = cam[0], cy = cam[1], cz = cam[2];
  const float c      = -0.7213475204444817f;   // -0.5 * log2(e)
  const float l2e    = 1.4426950408889634f;
  const float n2l2e  = -2.8853900817779268f;   // -2*log2(e)
  const float SH_C0  = 0.28209479177387814f;

  // ---------------- Phase 0: precompute + cull + ballot-compact ------------
  #pragma unroll
  for (int i = 0; i < G_N / 512; ++i) {
    int g = tid + i * 512;
    float i0 = __builtin_amdgcn_exp2f(n2l2e * scales[3*g+0]);
    float i1 = __builtin_amdgcn_exp2f(n2l2e * scales[3*g+1]);
    float i2 = __builtin_amdgcn_exp2f(n2l2e * scales[3*g+2]);

    float qw = rots[4*g+0], qx = rots[4*g+1], qy = rots[4*g+2], qz = rots[4*g+3];
    float inv = __builtin_amdgcn_rsqf(qw*qw + qx*qx + qy*qy + qz*qz);
    qw *= inv; qx *= inv; qy *= inv; qz *= inv;

    float R00 = 1.f - 2.f*(qy*qy + qz*qz), R01 = 2.f*(qx*qy - qw*qz), R02 = 2.f*(qx*qz + qw*qy);
    float R10 = 2.f*(qx*qy + qw*qz), R11 = 1.f - 2.f*(qx*qx + qz*qz), R12 = 2.f*(qy*qz - qw*qx);
    float R20 = 2.f*(qx*qz - qw*qy), R21 = 2.f*(qy*qz + qw*qx), R22 = 1.f - 2.f*(qx*qx + qy*qy);

    float p00 = c*(R00*R00*i0 + R01*R01*i1 + R02*R02*i2);
    float p11 = c*(R10*R10*i0 + R11*R11*i1 + R12*R12*i2);
    float p22 = c*(R20*R20*i0 + R21*R21*i1 + R22*R22*i2);
    float p01 = c*(R00*R10*i0 + R01*R11*i1 + R02*R12*i2);
    float p02 = c*(R00*R20*i0 + R01*R21*i1 + R02*R22*i2);
    float p12 = c*(R10*R20*i0 + R11*R21*i1 + R12*R22*i2);

    float ox = cx - means[3*g+0], oy = cy - means[3*g+1], oz = cz - means[3*g+2];
    float Px = p00*ox + p01*oy + p02*oz;      // = c * (P om)
    float Py = p01*ox + p11*oy + p12*oz;
    float Pz = p02*ox + p12*oy + p22*oz;
    float Cq = ox*Px + oy*Py + oz*Pz;         // = c * om^T P om

    float u  = __builtin_amdgcn_exp2f(-l2e * opacs[g]);
    float Cf = Cq - __builtin_amdgcn_logf(1.0f + u);   // + log2(sigmoid)

    float a0 = fmaxf(SH_C0*feats[3*g+0] + 0.5f, 0.f);
    float a1 = fmaxf(SH_C0*feats[3*g+1] + 0.5f, 0.f);
    float a2 = fmaxf(SH_C0*feats[3*g+2] + 0.5f, 0.f);
    float alb = (a0 + a1 + a2) * (1.0f/3.0f);

    #pragma unroll
    for (int r = 0; r < 2; ++r) {
      float A = p00*dXX[r] + p11*dYY[r] + p22*dzz + p01*dXY[r] + p02*dXZ[r] + p12*dYZ[r];
      float B = 2.f * (Px*dX[r] + Py*dY[r] + Pz*dz);
      // max over t in [0.5, 2.5]: A < 0 strictly (P positive definite)
      float tstar = fminf(2.5f, fmaxf(0.5f, -B / (2.f * A)));
      float qm = fmaf(fmaf(A, tstar, B), tstar, Cf);
      bool keep = qm > QCULL;
      unsigned long long m = __ballot(keep);
      int base;
      if (lane == 0) base = atomicAdd(&nact[r], __popcll(m));
      base = __shfl(base, 0, 64);
      if (keep) {
        int slot = base + __popcll(m & ((1ull << lane) - 1ull));
        *(float4*)&coef[r * PLANE + slot * 4] = make_float4(A, B, Cf, alb);
      }
    }
  }
  __syncthreads();

  // ---------------- Phase 1: hot loop over compacted records ----------------
  const int r  = lane >> 5;           // ray within pair
  const int ts = lane & 31;           // t-slot
  const float tstep = 2.0f / 63.0f;
  const float t0 = 0.5f + (float)ts * tstep;
  const float t1 = t0 + 32.f * tstep;

  const int n = nact[r];
  const float4* basep = (const float4*)&coef[r * PLANE];
  float d0 = 0.f, d1 = 0.f, h0 = 0.f, h1 = 0.f;
  for (int j = wv; j < n; j += 8) {
    float4 e = basep[j];
    float q0 = fmaf(fmaf(e.x, t0, e.y), t0, e.z);
    float q1 = fmaf(fmaf(e.x, t1, e.y), t1, e.z);
    float x0 = __builtin_amdgcn_exp2f(q0);
    float x1 = __builtin_amdgcn_exp2f(q1);
    d0 += x0; h0 = fmaf(x0, e.w, h0);
    d1 += x1; h1 = fmaf(x1, e.w, h1);
  }

  // ---------------- Phase 2: stash partials ----------------
  red[0][wv][r*64 + ts     ] = d0;  red[1][wv][r*64 + ts     ] = h0;
  red[0][wv][r*64 + ts + 32] = d1;  red[1][wv][r*64 + ts + 32] = h1;
  __syncthreads();

  // ---------------- Phase 3: reduce + scan + store (first 2 waves) ---------
  if (tid < 128) {
    const int rr = tid >> 6;
    const int t  = tid & 63;
    int idx = rr * 64 + t;
    float D  = ((red[0][0][idx] + red[0][1][idx]) + (red[0][2][idx] + red[0][3][idx]))
             + ((red[0][4][idx] + red[0][5][idx]) + (red[0][6][idx] + red[0][7][idx]));
    float Rh = ((red[1][0][idx] + red[1][1][idx]) + (red[1][2][idx] + red[1][3][idx]))
             + ((red[1][4][idx] + red[1][5][idx]) + (red[1][6][idx] + red[1][7][idx]));
    const float step = 1.0f * 0.03125f;   // C_LIGHT * DELTA_T
    float s = D * step;
    float inc = s;
    #pragma unroll
    for (int off = 1; off < 64; off <<= 1) {
      float v = __shfl_up(inc, off, 64);
      if (t >= off) inc += v;
    }
    float excl = inc - s;
    float T = __builtin_amdgcn_exp2f(-1.4426950408889634f * excl);
    float tv = 0.5f + (float)t * tstep;
    float res = Rh * T / (tv * tv + 1e-8f) * sth;
    out[t * NRAY + ray0 + rr] = res;
  }
}

// ---------------------------------------------------------------------------
// Histogram. One block per t bin; sum 1024 rays.
// ---------------------------------------------------------------------------
__global__ __launch_bounds__(256) void k_hist(const float* __restrict__ res,
                                              float* __restrict__ hist) {
  const int t = blockIdx.x;
  const int tid = threadIdx.x;
  float s = 0.f;
  #pragma unroll
  for (int rr = tid; rr < NRAY; rr += 256) s += res[t * NRAY + rr];
  #pragma unroll
  for (int off = 32; off > 0; off >>= 1) s += __shfl_down(s, off, 64);
  __shared__ float sm[4];
  if ((tid & 63) == 0) sm[tid >> 6] = s;
  __syncthreads();
  if (tid == 0) {
    const float dtdp = (float)((M_PI / 2.0 / NT) * (M_PI / NP));
    hist[t] = ((sm[0] + sm[1]) + (sm[2] + sm[3])) * dtdp;
  }
}

extern "C" void kernel_launch(void* const* d_in, const int* in_sizes, int n_in,
                              void* d_out, int out_size, void* d_ws, size_t ws_size,
                              hipStream_t stream) {
  const float* means  = (const float*)d_in[0];
  const float* scales = (const float*)d_in[1];
  const float* rots   = (const float*)d_in[2];
  const float* opacs  = (const float*)d_in[3];
  const float* feats  = (const float*)d_in[4];
  const float* cam    = (const float*)d_in[5];

  float* out = (float*)d_out;

  k_main<<<NRAY / 2, 512, 0, stream>>>(means, scales, rots, opacs, feats, cam, out);
  k_hist<<<NR,       256, 0, stream>>>(out, out + NR * NRAY);
}